// Round 14
// baseline (260.794 us; speedup 1.0000x reference)
//
#include <hip/hip_runtime.h>
#include <hip/hip_bf16.h>
#include <cstdint>
#include <cstddef>

// Problem constants
#define SEQ   2048
#define HID   2048
#define NH    32
#define NKVH  8
#define HD    64
#define KVDIM (NKVH * HD)   // 512

typedef __bf16 bf16_t;
typedef __bf16 bf16x8 __attribute__((ext_vector_type(8)));
typedef __bf16 bf16x4 __attribute__((ext_vector_type(4)));
typedef short  s16x4  __attribute__((ext_vector_type(4)));
typedef float  f32x4  __attribute__((ext_vector_type(4)));

// log2(10000)/32  (RoPE: theta^(-d/32) = exp2(-d*L))
#define ROPE_L 0.4152410118609203f
// Q pre-scale: log2(e)/sqrt(HD) — folded into qkv fp32 epilogue (single bf16
// round) so attention uses exp2 directly.
#define QSCALE 0.18033688011112043f

__device__ __forceinline__ bf16x8 load8(const float* p) {
    const float4 lo = *(const float4*)p;
    const float4 hi = *(const float4*)(p + 4);
    bf16x8 r;
    r[0] = (bf16_t)lo.x; r[1] = (bf16_t)lo.y; r[2] = (bf16_t)lo.z; r[3] = (bf16_t)lo.w;
    r[4] = (bf16_t)hi.x; r[5] = (bf16_t)hi.y; r[6] = (bf16_t)hi.z; r[7] = (bf16_t)hi.w;
    return r;
}

// async global->LDS, 16B per lane; LDS dest = wave-uniform base + lane*16
__device__ __forceinline__ void load_lds16(const bf16_t* g, bf16_t* l) {
    __builtin_amdgcn_global_load_lds((const __attribute__((address_space(1))) void*)g,
                                     (__attribute__((address_space(3))) void*)l,
                                     16, 0, 0);
}

// ---------------------------------------------------------------------------
// One-shot fp32 -> bf16 conversion of all GEMM operands (X, Wq, Wk, Wv, Wo).
// ---------------------------------------------------------------------------
#define NX  (SEQ * HID)          // 4M
#define NWQ (NH * HD * HID)      // 4M
#define NWK (KVDIM * HID)        // 1M
#define NWV (KVDIM * HID)        // 1M
#define NWO (HID * NH * HD)      // 4M
#define NTOT (NX + NWQ + NWK + NWV + NWO)   // 14M

__global__ __launch_bounds__(256) void cvt_all(const float* __restrict__ X,
                                               const float* __restrict__ Wq,
                                               const float* __restrict__ Wk,
                                               const float* __restrict__ Wv,
                                               const float* __restrict__ Wo,
                                               bf16_t* __restrict__ Xb,
                                               bf16_t* __restrict__ Wqb,
                                               bf16_t* __restrict__ Wkb,
                                               bf16_t* __restrict__ Wvb,
                                               bf16_t* __restrict__ Wob)
{
    size_t i = ((size_t)blockIdx.x * 256 + threadIdx.x) * 8;
    if (i >= NTOT) return;
    const size_t E0 = NX, E1 = E0 + NWQ, E2 = E1 + NWK, E3 = E2 + NWV;
    const float* s; bf16_t* d; size_t off;
    if (i < E0)      { s = X;  d = Xb;  off = i; }
    else if (i < E1) { s = Wq; d = Wqb; off = i - E0; }
    else if (i < E2) { s = Wk; d = Wkb; off = i - E1; }
    else if (i < E3) { s = Wv; d = Wvb; off = i - E2; }
    else             { s = Wo; d = Wob; off = i - E3; }
    *(bf16x8*)(d + off) = load8(s + off);
}

// ---------------------------------------------------------------------------
// Fused QKV projection + RoPE, 128x64 tiles (768 blocks = 3/CU).
// 4 waves stacked on M; each wave 32m x 64n = 2x4 mfma_f32_16x16x32_bf16.
// Q pre-scaled by QSCALE (fp32 multiply before the single bf16 round).
// V written transposed [KVDIM][SEQ].
// ---------------------------------------------------------------------------
__global__ __launch_bounds__(256) void qkv_gemm(const bf16_t* __restrict__ Xb,
                                                const bf16_t* __restrict__ Wqb,
                                                const bf16_t* __restrict__ Wkb,
                                                const bf16_t* __restrict__ Wvb,
                                                bf16_t* __restrict__ Qb,
                                                bf16_t* __restrict__ Kb,
                                                bf16_t* __restrict__ Vt)
{
    __shared__ alignas(16) bf16_t sa[128 * 32];
    __shared__ alignas(16) bf16_t sb[64 * 32];
    const int t = threadIdx.x;
    const int lane = t & 63;
    const int w  = t >> 6;
    const int n16 = lane & 15;
    const int q4  = lane >> 4;
    f32x4 acc[2][4] = {};

    const int m0 = blockIdx.x * 128;
    const int n0 = blockIdx.y * 64;

    const bf16_t* B;
    int mode, nc;
    if (n0 < NH * HD)              { B = Wqb + (size_t)n0 * HID;                     mode = 0; nc = n0; }
    else if (n0 < NH * HD + KVDIM) { B = Wkb + (size_t)(n0 - NH * HD) * HID;         mode = 1; nc = n0 - NH * HD; }
    else                           { B = Wvb + (size_t)(n0 - NH * HD - KVDIM) * HID; mode = 2; nc = n0 - NH * HD - KVDIM; }

    const int lrow = lane >> 2;          // 0..15
    const int lcol = (lane & 3) * 8;
    const bf16_t* ag = Xb + (size_t)(m0 + w * 32 + lrow) * HID + lcol;
    const bf16_t* bg = B  + (size_t)(w * 16 + lrow) * HID + lcol;
    bf16_t* la0 = &sa[(w * 32) * 32];
    bf16_t* la1 = &sa[(w * 32 + 16) * 32];
    bf16_t* lb0 = &sb[(w * 16) * 32];

    for (int k0 = 0; k0 < HID; k0 += 32) {
        load_lds16(ag + k0, la0);
        load_lds16(ag + k0 + (size_t)16 * HID, la1);
        load_lds16(bg + k0, lb0);
        __syncthreads();
        bf16x8 bfrag[4];
#pragma unroll
        for (int j = 0; j < 4; ++j)
            bfrag[j] = *(const bf16x8*)&sb[(j * 16 + n16) * 32 + q4 * 8];
#pragma unroll
        for (int i = 0; i < 2; ++i) {
            bf16x8 af = *(const bf16x8*)&sa[(w * 32 + i * 16 + n16) * 32 + q4 * 8];
#pragma unroll
            for (int j = 0; j < 4; ++j)
                acc[i][j] = __builtin_amdgcn_mfma_f32_16x16x32_bf16(af, bfrag[j], acc[i][j], 0, 0, 0);
        }
        __syncthreads();
    }

    if (mode < 2) {
        // ---- RoPE in registers: d = jt*16+n16 (jt<2), partner at jt+2 ----
#pragma unroll
        for (int jt = 0; jt < 2; ++jt) {
            float dd = (float)(jt * 16 + n16);
            float inv = exp2f(-dd * ROPE_L);
#pragma unroll
            for (int i = 0; i < 2; ++i) {
#pragma unroll
                for (int r = 0; r < 4; ++r) {
                    int pos = m0 + w * 32 + i * 16 + q4 * 4 + r;
                    float ang = (float)pos * inv;
                    float sn, cs;
                    sincosf(ang, &sn, &cs);
                    float x1 = acc[i][jt][r], x2 = acc[i][jt + 2][r];
                    acc[i][jt][r]     = x1 * cs - x2 * sn;
                    acc[i][jt + 2][r] = x2 * cs + x1 * sn;
                }
            }
        }
        const float osc = (mode == 0) ? QSCALE : 1.0f;   // Q: fold log2e/sqrt(HD)
        bf16_t* dst = (mode == 0) ? Qb : Kb;
        const int ld = (mode == 0) ? NH * HD : KVDIM;
#pragma unroll
        for (int i = 0; i < 2; ++i)
#pragma unroll
            for (int j = 0; j < 4; ++j) {
                int row = m0 + w * 32 + i * 16 + q4 * 4;
                int col = nc + j * 16 + n16;
#pragma unroll
                for (int r = 0; r < 4; ++r)
                    dst[(size_t)(row + r) * ld + col] = (bf16_t)(acc[i][j][r] * osc);
            }
    } else {
        // ---- V: store transposed, 4 consecutive rows per lane contiguous ----
#pragma unroll
        for (int i = 0; i < 2; ++i)
#pragma unroll
            for (int j = 0; j < 4; ++j) {
                int row = m0 + w * 32 + i * 16 + q4 * 4;
                int col = nc + j * 16 + n16;
#pragma unroll
                for (int r = 0; r < 4; ++r)
                    Vt[(size_t)col * SEQ + row + r] = (bf16_t)acc[i][j][r];
            }
    }
}

// ---------------------------------------------------------------------------
// O projection, 128x64 tiles (512 blocks = 2/CU), direct stores.
// ---------------------------------------------------------------------------
__global__ __launch_bounds__(256) void o_gemm(const bf16_t* __restrict__ A,
                                              const bf16_t* __restrict__ Bw,
                                              float* __restrict__ C)
{
    __shared__ alignas(16) bf16_t sa[128 * 32];
    __shared__ alignas(16) bf16_t sb[64 * 32];
    const int t = threadIdx.x;
    const int lane = t & 63;
    const int w  = t >> 6;
    const int n16 = lane & 15;
    const int q4  = lane >> 4;
    f32x4 acc[2][4] = {};

    const int m0 = blockIdx.x * 128;
    const int n0 = blockIdx.y * 64;

    const int lrow = lane >> 2;          // 0..15
    const int lcol = (lane & 3) * 8;
    const bf16_t* ag = A  + (size_t)(m0 + w * 32 + lrow) * HID + lcol;
    const bf16_t* bg = Bw + (size_t)(n0 + w * 16 + lrow) * HID + lcol;
    bf16_t* la0 = &sa[(w * 32) * 32];
    bf16_t* la1 = &sa[(w * 32 + 16) * 32];
    bf16_t* lb0 = &sb[(w * 16) * 32];

    for (int k0 = 0; k0 < HID; k0 += 32) {
        load_lds16(ag + k0, la0);
        load_lds16(ag + k0 + (size_t)16 * HID, la1);
        load_lds16(bg + k0, lb0);
        __syncthreads();
        bf16x8 bfrag[4];
#pragma unroll
        for (int j = 0; j < 4; ++j)
            bfrag[j] = *(const bf16x8*)&sb[(j * 16 + n16) * 32 + q4 * 8];
#pragma unroll
        for (int i = 0; i < 2; ++i) {
            bf16x8 af = *(const bf16x8*)&sa[(w * 32 + i * 16 + n16) * 32 + q4 * 8];
#pragma unroll
            for (int j = 0; j < 4; ++j)
                acc[i][j] = __builtin_amdgcn_mfma_f32_16x16x32_bf16(af, bfrag[j], acc[i][j], 0, 0, 0);
        }
        __syncthreads();
    }

#pragma unroll
    for (int i = 0; i < 2; ++i)
#pragma unroll
        for (int j = 0; j < 4; ++j) {
            int row = m0 + w * 32 + i * 16 + q4 * 4;
            int col = n0 + j * 16 + n16;
#pragma unroll
            for (int r = 0; r < 4; ++r)
                C[(size_t)(row + r) * HID + col] = acc[i][j][r];
        }
}

// ---------------------------------------------------------------------------
// MFMA causal flash attention, v8: R11's best staging (128 kv / barrier pair,
// Bq=64, no online softmax, deferred normalize) + REGISTER-ONLY P path:
//   S^T = mfma(K_frag, Q_frag)  -> thread (q4,n16) holds
//   P[q=n16][c=jt*16+q4*4+r], which IS the A-fragment layout of the K=16
//   MFMA (row=lane&15, k=(lane>>4)*4+j). PV then uses 16x
//   v_mfma_f32_16x16x16_bf16 with A packed straight from exp2 results —
//   no LDS round-trip for P (psA/psB deleted; LDS 40->32 KB).
// l is one scalar/thread (q-row n16); 2-step shuffle reduce at end.
// O lands in C-layout rows q4*4+r — same epilogue as before.
// ---------------------------------------------------------------------------
__global__ __launch_bounds__(256) void attn_mfma(const bf16_t* __restrict__ Qm,
                                                 const bf16_t* __restrict__ Km,
                                                 const bf16_t* __restrict__ Vt,
                                                 bf16_t* __restrict__ Om)
{
    const int h   = blockIdx.x & (NH - 1);
    const int qt  = (SEQ / 64 - 1) - (blockIdx.x >> 5);   // heavy first
    const int q0  = qt * 64;
    const int kvh = h >> 2;            // H/KVH = 4
    const int t   = threadIdx.x;
    const int w   = t >> 6;
    const int lane = t & 63;
    const int n16 = lane & 15;
    const int q4  = lane >> 4;

    // 32 KB: K 128x64 d-halves (8 KB x2), V^T 64x128 in 4 c-chunks (4 KB x4)
    __shared__ alignas(16) bf16_t kA[128 * 32];
    __shared__ alignas(16) bf16_t kB[128 * 32];
    __shared__ alignas(16) bf16_t vc[4][64 * 32];

    // Q fragments (B-operand layout == A layout), rows q0+w*16+n16
    const int qrow = q0 + w * 16 + n16;
    const bf16_t* qbase = Qm + (size_t)qrow * HID + h * HD;
    const bf16x8 qf0 = *(const bf16x8*)(qbase + q4 * 8);
    const bf16x8 qf1 = *(const bf16x8*)(qbase + 32 + q4 * 8);

    f32x4 acc[4] = {};
    float l_p = 0.0f;                   // per-thread partial sum, q-row = n16

    const int srow = lane >> 2;          // 0..15
    const int scol = (lane & 3) * 8;
    const bf16_t* kg = Km + (size_t)kvh * HD + scol;
    const bf16_t* vg = Vt + (size_t)(kvh * HD) * SEQ;

    const int nhalf = qt + 1;            // 64-kv halves

    for (int kb = 0; kb * 2 < nhalf; ++kb) {
        const int k0 = kb * 128;
        // ---- stage K (128x64) and V^T (64x128) via global_load_lds ----
        {
            const int r0 = w * 16 + srow;
            const bf16_t* kp0 = kg + (size_t)(k0 + r0) * KVDIM;
            const bf16_t* kp1 = kg + (size_t)(k0 + 64 + r0) * KVDIM;
            load_lds16(kp0,      &kA[(w * 16) * 32]);
            load_lds16(kp0 + 32, &kB[(w * 16) * 32]);
            load_lds16(kp1,      &kA[(64 + w * 16) * 32]);
            load_lds16(kp1 + 32, &kB[(64 + w * 16) * 32]);
            const bf16_t* vp = vg + (size_t)r0 * SEQ + k0 + scol;
            load_lds16(vp,      &vc[0][(w * 16) * 32]);
            load_lds16(vp + 32, &vc[1][(w * 16) * 32]);
            load_lds16(vp + 64, &vc[2][(w * 16) * 32]);
            load_lds16(vp + 96, &vc[3][(w * 16) * 32]);
        }
        __syncthreads();

#pragma unroll
        for (int hh = 0; hh < 2; ++hh) {
            const int gh = 2 * kb + hh;
            if (gh >= nhalf) break;                        // wave-uniform
            const bf16_t* kAh = &kA[hh * 64 * 32];
            const bf16_t* kBh = &kB[hh * 64 * 32];

            // ---- S^T = K Q^T (log2-domain): st[jt][r] = P-pre[q=n16][c=jt*16+q4*4+r]
            f32x4 st[4];
#pragma unroll
            for (int jt = 0; jt < 4; ++jt) {
                bf16x8 kf0 = *(const bf16x8*)&kAh[(jt * 16 + n16) * 32 + q4 * 8];
                bf16x8 kf1 = *(const bf16x8*)&kBh[(jt * 16 + n16) * 32 + q4 * 8];
                f32x4 s = {};
                s = __builtin_amdgcn_mfma_f32_16x16x32_bf16(kf0, qf0, s, 0, 0, 0);
                s = __builtin_amdgcn_mfma_f32_16x16x32_bf16(kf1, qf1, s, 0, 0, 0);
                st[jt] = s;
            }

            // ---- causal mask: diagonal half only (c > q) ----
            if (gh == qt) {
#pragma unroll
                for (int jt = 0; jt < 4; ++jt) {
                    int colg = gh * 64 + jt * 16 + q4 * 4;
#pragma unroll
                    for (int r = 0; r < 4; ++r)
                        if (colg + r > q0 + w * 16 + n16) st[jt][r] = -1e30f;
                }
            }

            // ---- exp2 + pack P A-frags in registers (no LDS) ----
            s16x4 pa[4];
#pragma unroll
            for (int jt = 0; jt < 4; ++jt) {
                bf16x4 pk;
#pragma unroll
                for (int r = 0; r < 4; ++r) {
                    float p = exp2f(st[jt][r]);
                    l_p += p;
                    pk[r] = (bf16_t)p;
                }
                pa[jt] = __builtin_bit_cast(s16x4, pk);
            }

            // ---- O += P V via 16x16x16 MFMA (B = V^T 8-byte reads) ----
#pragma unroll
            for (int jd = 0; jd < 4; ++jd) {
#pragma unroll
                for (int jc = 0; jc < 4; ++jc) {
                    const bf16_t* vb = &vc[hh * 2 + (jc >> 1)]
                        [(jd * 16 + n16) * 32 + (jc & 1) * 16 + q4 * 4];
                    s16x4 vf = __builtin_bit_cast(s16x4, *(const bf16x4*)vb);
                    acc[jd] = __builtin_amdgcn_mfma_f32_16x16x16bf16_1k(pa[jc], vf, acc[jd], 0, 0, 0);
                }
            }
        }
        __syncthreads();   // protect K/V LDS before restaging
    }

    // ---- reduce l across the 4 lanes sharing n16 (q4 groups) ----
    l_p += __shfl_xor(l_p, 16);
    l_p += __shfl_xor(l_p, 32);

    // redistribute: acc rows are q = q4*4+r; l for that q lives at lane q4*4+r
    float linv[4];
#pragma unroll
    for (int r = 0; r < 4; ++r)
        linv[r] = 1.0f / __shfl(l_p, q4 * 4 + r);

#pragma unroll
    for (int jd = 0; jd < 4; ++jd)
#pragma unroll
        for (int r = 0; r < 4; ++r) {
            int rowg = q0 + w * 16 + q4 * 4 + r;
            Om[(size_t)rowg * HID + h * HD + jd * 16 + n16] = (bf16_t)(acc[jd][r] * linv[r]);
        }
}

// ---------------------------------------------------------------------------
extern "C" void kernel_launch(void* const* d_in, const int* in_sizes, int n_in,
                              void* d_out, int out_size, void* d_ws, size_t ws_size,
                              hipStream_t stream)
{
    const float* X  = (const float*)d_in[0];
    const float* Wq = (const float*)d_in[1];
    const float* Wk = (const float*)d_in[2];
    const float* Wv = (const float*)d_in[3];
    const float* Wo = (const float*)d_in[4];
    float* out = (float*)d_out;

    bf16_t* Xb  = (bf16_t*)d_ws;                      // [SEQ][HID]     8 MB
    bf16_t* Wqb = Xb  + (size_t)NX;                   // [2048][2048]   8 MB
    bf16_t* Wkb = Wqb + (size_t)NWQ;                  // [512][2048]    2 MB
    bf16_t* Wvb = Wkb + (size_t)NWK;                  // [512][2048]    2 MB
    bf16_t* Wob = Wvb + (size_t)NWV;                  // [2048][2048]   8 MB
    bf16_t* Qb  = Wob + (size_t)NWO;                  // [SEQ][NH*HD]   8 MB (pre-scaled log2e/8)
    bf16_t* Kb  = Qb  + (size_t)SEQ * (NH * HD);      // [SEQ][KVDIM]   2 MB
    bf16_t* Vt  = Kb  + (size_t)SEQ * KVDIM;          // [KVDIM][SEQ]   2 MB
    bf16_t* Ob  = Vt  + (size_t)SEQ * KVDIM;          // [SEQ][NH*HD]   8 MB

    dim3 blk(256);

    // one-shot fp32 -> bf16 conversion of all operands
    cvt_all<<<dim3((NTOT / 8 + 255) / 256), blk, 0, stream>>>(X, Wq, Wk, Wv, Wo, Xb, Wqb, Wkb, Wvb, Wob);

    // fused QKV projection + RoPE (128x64 tiles, 768 blocks = 3/CU)
    qkv_gemm<<<dim3(SEQ / 128, (NH * HD + 2 * KVDIM) / 64), blk, 0, stream>>>(Xb, Wqb, Wkb, Wvb, Qb, Kb, Vt);

    // causal GQA attention (flash v8: 128-kv staging, register-only P path)
    attn_mfma<<<dim3((SEQ / 64) * NH), blk, 0, stream>>>(Qb, Kb, Vt, Ob);

    // output projection -> d_out (128x64 tiles, direct stores)
    o_gemm<<<dim3(SEQ / 128, HID / 64), blk, 0, stream>>>(Ob, Wob, out);
}

// Round 15
// 221.362 us; speedup vs baseline: 1.1781x; 1.1781x over previous
//
#include <hip/hip_runtime.h>
#include <hip/hip_bf16.h>
#include <cstdint>
#include <cstddef>

// Problem constants
#define SEQ   2048
#define HID   2048
#define NH    32
#define NKVH  8
#define HD    64
#define KVDIM (NKVH * HD)   // 512

typedef __bf16 bf16_t;
typedef __bf16 bf16x8 __attribute__((ext_vector_type(8)));
typedef float  f32x4  __attribute__((ext_vector_type(4)));

// log2(10000)/32  (RoPE: theta^(-d/32) = exp2(-d*L))
#define ROPE_L 0.4152410118609203f
// Q pre-scale: log2(e)/sqrt(HD) — folded into qkv fp32 epilogue (single bf16
// round) so attention uses exp2 directly (saves the v_mul inside __expf).
#define QSCALE 0.18033688011112043f

__device__ __forceinline__ bf16x8 load8(const float* p) {
    const float4 lo = *(const float4*)p;
    const float4 hi = *(const float4*)(p + 4);
    bf16x8 r;
    r[0] = (bf16_t)lo.x; r[1] = (bf16_t)lo.y; r[2] = (bf16_t)lo.z; r[3] = (bf16_t)lo.w;
    r[4] = (bf16_t)hi.x; r[5] = (bf16_t)hi.y; r[6] = (bf16_t)hi.z; r[7] = (bf16_t)hi.w;
    return r;
}

// async global->LDS, 16B per lane; LDS dest = wave-uniform base + lane*16
__device__ __forceinline__ void load_lds16(const bf16_t* g, bf16_t* l) {
    __builtin_amdgcn_global_load_lds((const __attribute__((address_space(1))) void*)g,
                                     (__attribute__((address_space(3))) void*)l,
                                     16, 0, 0);
}

// ---------------------------------------------------------------------------
// One-shot fp32 -> bf16 conversion of all GEMM operands (X, Wq, Wk, Wv, Wo).
// ---------------------------------------------------------------------------
#define NX  (SEQ * HID)          // 4M
#define NWQ (NH * HD * HID)      // 4M
#define NWK (KVDIM * HID)        // 1M
#define NWV (KVDIM * HID)        // 1M
#define NWO (HID * NH * HD)      // 4M
#define NTOT (NX + NWQ + NWK + NWV + NWO)   // 14M

__global__ __launch_bounds__(256) void cvt_all(const float* __restrict__ X,
                                               const float* __restrict__ Wq,
                                               const float* __restrict__ Wk,
                                               const float* __restrict__ Wv,
                                               const float* __restrict__ Wo,
                                               bf16_t* __restrict__ Xb,
                                               bf16_t* __restrict__ Wqb,
                                               bf16_t* __restrict__ Wkb,
                                               bf16_t* __restrict__ Wvb,
                                               bf16_t* __restrict__ Wob)
{
    size_t i = ((size_t)blockIdx.x * 256 + threadIdx.x) * 8;
    if (i >= NTOT) return;
    const size_t E0 = NX, E1 = E0 + NWQ, E2 = E1 + NWK, E3 = E2 + NWV;
    const float* s; bf16_t* d; size_t off;
    if (i < E0)      { s = X;  d = Xb;  off = i; }
    else if (i < E1) { s = Wq; d = Wqb; off = i - E0; }
    else if (i < E2) { s = Wk; d = Wkb; off = i - E1; }
    else if (i < E3) { s = Wv; d = Wvb; off = i - E2; }
    else             { s = Wo; d = Wob; off = i - E3; }
    *(bf16x8*)(d + off) = load8(s + off);
}

// ---------------------------------------------------------------------------
// Fused QKV projection + RoPE, 128x64 tiles (768 blocks = 3/CU).
// 4 waves stacked on M; each wave 32m x 64n = 2x4 mfma_f32_16x16x32_bf16.
// Q pre-scaled by QSCALE (fp32 multiply before the single bf16 round).
// V written transposed [KVDIM][SEQ].
// ---------------------------------------------------------------------------
__global__ __launch_bounds__(256) void qkv_gemm(const bf16_t* __restrict__ Xb,
                                                const bf16_t* __restrict__ Wqb,
                                                const bf16_t* __restrict__ Wkb,
                                                const bf16_t* __restrict__ Wvb,
                                                bf16_t* __restrict__ Qb,
                                                bf16_t* __restrict__ Kb,
                                                bf16_t* __restrict__ Vt)
{
    __shared__ alignas(16) bf16_t sa[128 * 32];
    __shared__ alignas(16) bf16_t sb[64 * 32];
    const int t = threadIdx.x;
    const int lane = t & 63;
    const int w  = t >> 6;
    const int n16 = lane & 15;
    const int q4  = lane >> 4;
    f32x4 acc[2][4] = {};

    const int m0 = blockIdx.x * 128;
    const int n0 = blockIdx.y * 64;

    const bf16_t* B;
    int mode, nc;
    if (n0 < NH * HD)              { B = Wqb + (size_t)n0 * HID;                     mode = 0; nc = n0; }
    else if (n0 < NH * HD + KVDIM) { B = Wkb + (size_t)(n0 - NH * HD) * HID;         mode = 1; nc = n0 - NH * HD; }
    else                           { B = Wvb + (size_t)(n0 - NH * HD - KVDIM) * HID; mode = 2; nc = n0 - NH * HD - KVDIM; }

    const int lrow = lane >> 2;          // 0..15
    const int lcol = (lane & 3) * 8;
    const bf16_t* ag = Xb + (size_t)(m0 + w * 32 + lrow) * HID + lcol;
    const bf16_t* bg = B  + (size_t)(w * 16 + lrow) * HID + lcol;
    bf16_t* la0 = &sa[(w * 32) * 32];
    bf16_t* la1 = &sa[(w * 32 + 16) * 32];
    bf16_t* lb0 = &sb[(w * 16) * 32];

    for (int k0 = 0; k0 < HID; k0 += 32) {
        load_lds16(ag + k0, la0);
        load_lds16(ag + k0 + (size_t)16 * HID, la1);
        load_lds16(bg + k0, lb0);
        __syncthreads();
        bf16x8 bfrag[4];
#pragma unroll
        for (int j = 0; j < 4; ++j)
            bfrag[j] = *(const bf16x8*)&sb[(j * 16 + n16) * 32 + q4 * 8];
#pragma unroll
        for (int i = 0; i < 2; ++i) {
            bf16x8 af = *(const bf16x8*)&sa[(w * 32 + i * 16 + n16) * 32 + q4 * 8];
#pragma unroll
            for (int j = 0; j < 4; ++j)
                acc[i][j] = __builtin_amdgcn_mfma_f32_16x16x32_bf16(af, bfrag[j], acc[i][j], 0, 0, 0);
        }
        __syncthreads();
    }

    if (mode < 2) {
        // ---- RoPE in registers: d = jt*16+n16 (jt<2), partner at jt+2 ----
#pragma unroll
        for (int jt = 0; jt < 2; ++jt) {
            float dd = (float)(jt * 16 + n16);
            float inv = exp2f(-dd * ROPE_L);
#pragma unroll
            for (int i = 0; i < 2; ++i) {
#pragma unroll
                for (int r = 0; r < 4; ++r) {
                    int pos = m0 + w * 32 + i * 16 + q4 * 4 + r;
                    float ang = (float)pos * inv;
                    float sn, cs;
                    sincosf(ang, &sn, &cs);
                    float x1 = acc[i][jt][r], x2 = acc[i][jt + 2][r];
                    acc[i][jt][r]     = x1 * cs - x2 * sn;
                    acc[i][jt + 2][r] = x2 * cs + x1 * sn;
                }
            }
        }
        const float osc = (mode == 0) ? QSCALE : 1.0f;   // Q: fold log2e/sqrt(HD)
        bf16_t* dst = (mode == 0) ? Qb : Kb;
        const int ld = (mode == 0) ? NH * HD : KVDIM;
#pragma unroll
        for (int i = 0; i < 2; ++i)
#pragma unroll
            for (int j = 0; j < 4; ++j) {
                int row = m0 + w * 32 + i * 16 + q4 * 4;
                int col = nc + j * 16 + n16;
#pragma unroll
                for (int r = 0; r < 4; ++r)
                    dst[(size_t)(row + r) * ld + col] = (bf16_t)(acc[i][j][r] * osc);
            }
    } else {
        // ---- V: store transposed, 4 consecutive rows per lane contiguous ----
#pragma unroll
        for (int i = 0; i < 2; ++i)
#pragma unroll
            for (int j = 0; j < 4; ++j) {
                int row = m0 + w * 32 + i * 16 + q4 * 4;
                int col = nc + j * 16 + n16;
#pragma unroll
                for (int r = 0; r < 4; ++r)
                    Vt[(size_t)col * SEQ + row + r] = (bf16_t)acc[i][j][r];
            }
    }
}

// ---------------------------------------------------------------------------
// O projection, 128x64 tiles (512 blocks = 2/CU), direct stores (R11 best).
// ---------------------------------------------------------------------------
__global__ __launch_bounds__(256) void o_gemm(const bf16_t* __restrict__ A,
                                              const bf16_t* __restrict__ Bw,
                                              float* __restrict__ C)
{
    __shared__ alignas(16) bf16_t sa[128 * 32];
    __shared__ alignas(16) bf16_t sb[64 * 32];
    const int t = threadIdx.x;
    const int lane = t & 63;
    const int w  = t >> 6;
    const int n16 = lane & 15;
    const int q4  = lane >> 4;
    f32x4 acc[2][4] = {};

    const int m0 = blockIdx.x * 128;
    const int n0 = blockIdx.y * 64;

    const int lrow = lane >> 2;          // 0..15
    const int lcol = (lane & 3) * 8;
    const bf16_t* ag = A  + (size_t)(m0 + w * 32 + lrow) * HID + lcol;
    const bf16_t* bg = Bw + (size_t)(n0 + w * 16 + lrow) * HID + lcol;
    bf16_t* la0 = &sa[(w * 32) * 32];
    bf16_t* la1 = &sa[(w * 32 + 16) * 32];
    bf16_t* lb0 = &sb[(w * 16) * 32];

    for (int k0 = 0; k0 < HID; k0 += 32) {
        load_lds16(ag + k0, la0);
        load_lds16(ag + k0 + (size_t)16 * HID, la1);
        load_lds16(bg + k0, lb0);
        __syncthreads();
        bf16x8 bfrag[4];
#pragma unroll
        for (int j = 0; j < 4; ++j)
            bfrag[j] = *(const bf16x8*)&sb[(j * 16 + n16) * 32 + q4 * 8];
#pragma unroll
        for (int i = 0; i < 2; ++i) {
            bf16x8 af = *(const bf16x8*)&sa[(w * 32 + i * 16 + n16) * 32 + q4 * 8];
#pragma unroll
            for (int j = 0; j < 4; ++j)
                acc[i][j] = __builtin_amdgcn_mfma_f32_16x16x32_bf16(af, bfrag[j], acc[i][j], 0, 0, 0);
        }
        __syncthreads();
    }

#pragma unroll
    for (int i = 0; i < 2; ++i)
#pragma unroll
        for (int j = 0; j < 4; ++j) {
            int row = m0 + w * 32 + i * 16 + q4 * 4;
            int col = n0 + j * 16 + n16;
#pragma unroll
            for (int r = 0; r < 4; ++r)
                C[(size_t)(row + r) * HID + col] = acc[i][j][r];
        }
}

// ---------------------------------------------------------------------------
// MFMA causal flash attention — R11's best configuration (v5): Bq=64,
// 128-kv staging per barrier pair (40 KB LDS, 4 blocks/CU), no online
// softmax (scores bounded; unnormalized O + per-thread l partials;
// lane-reduce + normalize at end), P via per-wave LDS round-trip.
// Only delta vs R11: exp2f with log2e folded into Q pre-scale (R12 rider).
// kv-staging sweep: 64=56us, 128=49us (best), 256=56us; register-P=94us.
// ---------------------------------------------------------------------------
__global__ __launch_bounds__(256) void attn_mfma(const bf16_t* __restrict__ Qm,
                                                 const bf16_t* __restrict__ Km,
                                                 const bf16_t* __restrict__ Vt,
                                                 bf16_t* __restrict__ Om)
{
    const int h   = blockIdx.x & (NH - 1);
    const int qt  = (SEQ / 64 - 1) - (blockIdx.x >> 5);   // heavy first
    const int q0  = qt * 64;
    const int kvh = h >> 2;            // H/KVH = 4
    const int t   = threadIdx.x;
    const int w   = t >> 6;
    const int lane = t & 63;
    const int n16 = lane & 15;
    const int q4  = lane >> 4;

    __shared__ alignas(16) bf16_t kA[128 * 32];
    __shared__ alignas(16) bf16_t kB[128 * 32];
    __shared__ alignas(16) bf16_t vc0[64 * 32], vc1[64 * 32];
    __shared__ alignas(16) bf16_t vc2[64 * 32], vc3[64 * 32];
    __shared__ alignas(16) bf16_t psA[4][16 * 32];
    __shared__ alignas(16) bf16_t psB[4][16 * 32];

    const int qrow = q0 + w * 16 + n16;
    const bf16_t* qbase = Qm + (size_t)qrow * HID + h * HD;
    const bf16x8 qf0 = *(const bf16x8*)(qbase + q4 * 8);
    const bf16x8 qf1 = *(const bf16x8*)(qbase + 32 + q4 * 8);

    f32x4 acc[4] = {};
    float l_p[4] = {0.f, 0.f, 0.f, 0.f};

    const int srow = lane >> 2;
    const int scol = (lane & 3) * 8;
    const bf16_t* kg = Km + (size_t)kvh * HD + scol;
    const bf16_t* vg = Vt + (size_t)(kvh * HD) * SEQ;

    const int rowg0 = q0 + w * 16 + q4 * 4;
    const int nhalf = qt + 1;

    for (int kb = 0; kb * 2 < nhalf; ++kb) {
        const int k0 = kb * 128;
        {
            const int r0 = w * 16 + srow;
            const bf16_t* kp0 = kg + (size_t)(k0 + r0) * KVDIM;
            const bf16_t* kp1 = kg + (size_t)(k0 + 64 + r0) * KVDIM;
            load_lds16(kp0,      &kA[(w * 16) * 32]);
            load_lds16(kp0 + 32, &kB[(w * 16) * 32]);
            load_lds16(kp1,      &kA[(64 + w * 16) * 32]);
            load_lds16(kp1 + 32, &kB[(64 + w * 16) * 32]);
            const bf16_t* vp = vg + (size_t)r0 * SEQ + k0 + scol;
            load_lds16(vp,      &vc0[(w * 16) * 32]);
            load_lds16(vp + 32, &vc1[(w * 16) * 32]);
            load_lds16(vp + 64, &vc2[(w * 16) * 32]);
            load_lds16(vp + 96, &vc3[(w * 16) * 32]);
        }
        __syncthreads();

#pragma unroll
        for (int hh = 0; hh < 2; ++hh) {
            const int gh = 2 * kb + hh;
            if (gh >= nhalf) break;                        // wave-uniform
            const bf16_t* kAh = &kA[hh * 64 * 32];
            const bf16_t* kBh = &kB[hh * 64 * 32];
            const bf16_t* vAh = hh ? vc2 : vc0;
            const bf16_t* vBh = hh ? vc3 : vc1;

            // ---- S' = Q' K^T (log2-domain scores) ----
            f32x4 st[4];
#pragma unroll
            for (int jt = 0; jt < 4; ++jt) {
                bf16x8 kf0 = *(const bf16x8*)&kAh[(jt * 16 + n16) * 32 + q4 * 8];
                bf16x8 kf1 = *(const bf16x8*)&kBh[(jt * 16 + n16) * 32 + q4 * 8];
                f32x4 s = {};
                s = __builtin_amdgcn_mfma_f32_16x16x32_bf16(qf0, kf0, s, 0, 0, 0);
                s = __builtin_amdgcn_mfma_f32_16x16x32_bf16(qf1, kf1, s, 0, 0, 0);
                st[jt] = s;
            }

            // ---- causal mask: diagonal half only ----
            if (gh == qt) {
#pragma unroll
                for (int jt = 0; jt < 4; ++jt) {
                    int colg = gh * 64 + jt * 16 + n16;
#pragma unroll
                    for (int r = 0; r < 4; ++r)
                        if (colg > rowg0 + r) st[jt][r] = -1e30f;
                }
            }

            // ---- exp2 + per-thread partial l ----
#pragma unroll
            for (int jt = 0; jt < 4; ++jt)
#pragma unroll
                for (int r = 0; r < 4; ++r) {
                    float p = exp2f(st[jt][r]);
                    st[jt][r] = p;
                    l_p[r] += p;
                }

            // ---- P: C-layout regs -> per-wave LDS (A-layout source) ----
#pragma unroll
            for (int jt = 0; jt < 4; ++jt) {
                bf16_t* ph = (jt < 2) ? psA[w] : psB[w];
                int c16 = (jt & 1) * 16;
#pragma unroll
                for (int r = 0; r < 4; ++r)
                    ph[(q4 * 4 + r) * 32 + c16 + n16] = (bf16_t)st[jt][r];
            }
            bf16x8 pf0 = *(const bf16x8*)&psA[w][n16 * 32 + q4 * 8];
            bf16x8 pf1 = *(const bf16x8*)&psB[w][n16 * 32 + q4 * 8];

            // ---- O += P V (unnormalized) ----
#pragma unroll
            for (int jd = 0; jd < 4; ++jd) {
                bf16x8 vf0 = *(const bf16x8*)&vAh[(jd * 16 + n16) * 32 + q4 * 8];
                bf16x8 vf1 = *(const bf16x8*)&vBh[(jd * 16 + n16) * 32 + q4 * 8];
                acc[jd] = __builtin_amdgcn_mfma_f32_16x16x32_bf16(pf0, vf0, acc[jd], 0, 0, 0);
                acc[jd] = __builtin_amdgcn_mfma_f32_16x16x32_bf16(pf1, vf1, acc[jd], 0, 0, 0);
            }
        }
        __syncthreads();
    }

    // ---- single lane-reduce of l, then normalize + store ----
#pragma unroll
    for (int msk = 1; msk < 16; msk <<= 1)
#pragma unroll
        for (int r = 0; r < 4; ++r)
            l_p[r] += __shfl_xor(l_p[r], msk);

    float linv[4];
#pragma unroll
    for (int r = 0; r < 4; ++r) linv[r] = 1.0f / l_p[r];
#pragma unroll
    for (int jd = 0; jd < 4; ++jd)
#pragma unroll
        for (int r = 0; r < 4; ++r) {
            int rowg = rowg0 + r;
            Om[(size_t)rowg * HID + h * HD + jd * 16 + n16] = (bf16_t)(acc[jd][r] * linv[r]);
        }
}

// ---------------------------------------------------------------------------
extern "C" void kernel_launch(void* const* d_in, const int* in_sizes, int n_in,
                              void* d_out, int out_size, void* d_ws, size_t ws_size,
                              hipStream_t stream)
{
    const float* X  = (const float*)d_in[0];
    const float* Wq = (const float*)d_in[1];
    const float* Wk = (const float*)d_in[2];
    const float* Wv = (const float*)d_in[3];
    const float* Wo = (const float*)d_in[4];
    float* out = (float*)d_out;

    bf16_t* Xb  = (bf16_t*)d_ws;                      // [SEQ][HID]     8 MB
    bf16_t* Wqb = Xb  + (size_t)NX;                   // [2048][2048]   8 MB
    bf16_t* Wkb = Wqb + (size_t)NWQ;                  // [512][2048]    2 MB
    bf16_t* Wvb = Wkb + (size_t)NWK;                  // [512][2048]    2 MB
    bf16_t* Wob = Wvb + (size_t)NWV;                  // [2048][2048]   8 MB
    bf16_t* Qb  = Wob + (size_t)NWO;                  // [SEQ][NH*HD]   8 MB (pre-scaled log2e/8)
    bf16_t* Kb  = Qb  + (size_t)SEQ * (NH * HD);      // [SEQ][KVDIM]   2 MB
    bf16_t* Vt  = Kb  + (size_t)SEQ * KVDIM;          // [KVDIM][SEQ]   2 MB
    bf16_t* Ob  = Vt  + (size_t)SEQ * KVDIM;          // [SEQ][NH*HD]   8 MB

    dim3 blk(256);

    // one-shot fp32 -> bf16 conversion of all operands
    cvt_all<<<dim3((NTOT / 8 + 255) / 256), blk, 0, stream>>>(X, Wq, Wk, Wv, Wo, Xb, Wqb, Wkb, Wvb, Wob);

    // fused QKV projection + RoPE (128x64 tiles, 768 blocks = 3/CU)
    qkv_gemm<<<dim3(SEQ / 128, (NH * HD + 2 * KVDIM) / 64), blk, 0, stream>>>(Xb, Wqb, Wkb, Wvb, Qb, Kb, Vt);

    // causal GQA attention (R11 best: 128-kv staging + exp2 rider)
    attn_mfma<<<dim3((SEQ / 64) * NH), blk, 0, stream>>>(Qb, Kb, Vt, Ob);

    // output projection -> d_out (128x64 tiles, direct stores)
    o_gemm<<<dim3(SEQ / 128, HID / 64), blk, 0, stream>>>(Ob, Wob, out);
}

// Round 16
// 213.653 us; speedup vs baseline: 1.2206x; 1.0361x over previous
//
#include <hip/hip_runtime.h>
#include <hip/hip_bf16.h>
#include <cstdint>
#include <cstddef>

// Problem constants
#define SEQ   2048
#define HID   2048
#define NH    32
#define NKVH  8
#define HD    64
#define KVDIM (NKVH * HD)   // 512

typedef __bf16 bf16_t;
typedef __bf16 bf16x8 __attribute__((ext_vector_type(8)));
typedef float  f32x4  __attribute__((ext_vector_type(4)));

// log2(10000)/32  (RoPE: theta^(-d/32) = exp2(-d*L))
#define ROPE_L 0.4152410118609203f

// exp path: raw v_exp_f32 (2^x) if the builtin exists — then Q carries
// log2(e)/sqrt(HD); otherwise __expf (v_mul+v_exp) with plain 1/sqrt(HD).
// (R15 lesson: libm exp2f is an OCML call — VALUBusy 32->41%, +6us.)
#if __has_builtin(__builtin_amdgcn_exp2f)
#define QSCALE 0.18033688011112043f
#define EXPFN(x) __builtin_amdgcn_exp2f(x)
#else
#define QSCALE 0.125f
#define EXPFN(x) __expf(x)
#endif

__device__ __forceinline__ bf16x8 load8(const float* p) {
    const float4 lo = *(const float4*)p;
    const float4 hi = *(const float4*)(p + 4);
    bf16x8 r;
    r[0] = (bf16_t)lo.x; r[1] = (bf16_t)lo.y; r[2] = (bf16_t)lo.z; r[3] = (bf16_t)lo.w;
    r[4] = (bf16_t)hi.x; r[5] = (bf16_t)hi.y; r[6] = (bf16_t)hi.z; r[7] = (bf16_t)hi.w;
    return r;
}

// async global->LDS, 16B per lane; LDS dest = wave-uniform base + lane*16
__device__ __forceinline__ void load_lds16(const bf16_t* g, bf16_t* l) {
    __builtin_amdgcn_global_load_lds((const __attribute__((address_space(1))) void*)g,
                                     (__attribute__((address_space(3))) void*)l,
                                     16, 0, 0);
}

// ---------------------------------------------------------------------------
// One-shot fp32 -> bf16 conversion of all GEMM operands (X, Wq, Wk, Wv, Wo).
// ---------------------------------------------------------------------------
#define NX  (SEQ * HID)          // 4M
#define NWQ (NH * HD * HID)      // 4M
#define NWK (KVDIM * HID)        // 1M
#define NWV (KVDIM * HID)        // 1M
#define NWO (HID * NH * HD)      // 4M
#define NTOT (NX + NWQ + NWK + NWV + NWO)   // 14M

__global__ __launch_bounds__(256) void cvt_all(const float* __restrict__ X,
                                               const float* __restrict__ Wq,
                                               const float* __restrict__ Wk,
                                               const float* __restrict__ Wv,
                                               const float* __restrict__ Wo,
                                               bf16_t* __restrict__ Xb,
                                               bf16_t* __restrict__ Wqb,
                                               bf16_t* __restrict__ Wkb,
                                               bf16_t* __restrict__ Wvb,
                                               bf16_t* __restrict__ Wob)
{
    size_t i = ((size_t)blockIdx.x * 256 + threadIdx.x) * 8;
    if (i >= NTOT) return;
    const size_t E0 = NX, E1 = E0 + NWQ, E2 = E1 + NWK, E3 = E2 + NWV;
    const float* s; bf16_t* d; size_t off;
    if (i < E0)      { s = X;  d = Xb;  off = i; }
    else if (i < E1) { s = Wq; d = Wqb; off = i - E0; }
    else if (i < E2) { s = Wk; d = Wkb; off = i - E1; }
    else if (i < E3) { s = Wv; d = Wvb; off = i - E2; }
    else             { s = Wo; d = Wob; off = i - E3; }
    *(bf16x8*)(d + off) = load8(s + off);
}

// ---------------------------------------------------------------------------
// Fused QKV projection + RoPE, 128x64 tiles (768 blocks = 3/CU).
// 4 waves stacked on M; each wave 32m x 64n = 2x4 mfma_f32_16x16x32_bf16.
// Q pre-scaled by QSCALE (fp32 multiply before the single bf16 round).
// V written transposed [KVDIM][SEQ].
// ---------------------------------------------------------------------------
__global__ __launch_bounds__(256) void qkv_gemm(const bf16_t* __restrict__ Xb,
                                                const bf16_t* __restrict__ Wqb,
                                                const bf16_t* __restrict__ Wkb,
                                                const bf16_t* __restrict__ Wvb,
                                                bf16_t* __restrict__ Qb,
                                                bf16_t* __restrict__ Kb,
                                                bf16_t* __restrict__ Vt)
{
    __shared__ alignas(16) bf16_t sa[128 * 32];
    __shared__ alignas(16) bf16_t sb[64 * 32];
    const int t = threadIdx.x;
    const int lane = t & 63;
    const int w  = t >> 6;
    const int n16 = lane & 15;
    const int q4  = lane >> 4;
    f32x4 acc[2][4] = {};

    const int m0 = blockIdx.x * 128;
    const int n0 = blockIdx.y * 64;

    const bf16_t* B;
    int mode, nc;
    if (n0 < NH * HD)              { B = Wqb + (size_t)n0 * HID;                     mode = 0; nc = n0; }
    else if (n0 < NH * HD + KVDIM) { B = Wkb + (size_t)(n0 - NH * HD) * HID;         mode = 1; nc = n0 - NH * HD; }
    else                           { B = Wvb + (size_t)(n0 - NH * HD - KVDIM) * HID; mode = 2; nc = n0 - NH * HD - KVDIM; }

    const int lrow = lane >> 2;          // 0..15
    const int lcol = (lane & 3) * 8;
    const bf16_t* ag = Xb + (size_t)(m0 + w * 32 + lrow) * HID + lcol;
    const bf16_t* bg = B  + (size_t)(w * 16 + lrow) * HID + lcol;
    bf16_t* la0 = &sa[(w * 32) * 32];
    bf16_t* la1 = &sa[(w * 32 + 16) * 32];
    bf16_t* lb0 = &sb[(w * 16) * 32];

    for (int k0 = 0; k0 < HID; k0 += 32) {
        load_lds16(ag + k0, la0);
        load_lds16(ag + k0 + (size_t)16 * HID, la1);
        load_lds16(bg + k0, lb0);
        __syncthreads();
        bf16x8 bfrag[4];
#pragma unroll
        for (int j = 0; j < 4; ++j)
            bfrag[j] = *(const bf16x8*)&sb[(j * 16 + n16) * 32 + q4 * 8];
#pragma unroll
        for (int i = 0; i < 2; ++i) {
            bf16x8 af = *(const bf16x8*)&sa[(w * 32 + i * 16 + n16) * 32 + q4 * 8];
#pragma unroll
            for (int j = 0; j < 4; ++j)
                acc[i][j] = __builtin_amdgcn_mfma_f32_16x16x32_bf16(af, bfrag[j], acc[i][j], 0, 0, 0);
        }
        __syncthreads();
    }

    if (mode < 2) {
        // ---- RoPE in registers: d = jt*16+n16 (jt<2), partner at jt+2 ----
#pragma unroll
        for (int jt = 0; jt < 2; ++jt) {
            float dd = (float)(jt * 16 + n16);
            float inv = exp2f(-dd * ROPE_L);
#pragma unroll
            for (int i = 0; i < 2; ++i) {
#pragma unroll
                for (int r = 0; r < 4; ++r) {
                    int pos = m0 + w * 32 + i * 16 + q4 * 4 + r;
                    float ang = (float)pos * inv;
                    float sn, cs;
                    sincosf(ang, &sn, &cs);
                    float x1 = acc[i][jt][r], x2 = acc[i][jt + 2][r];
                    acc[i][jt][r]     = x1 * cs - x2 * sn;
                    acc[i][jt + 2][r] = x2 * cs + x1 * sn;
                }
            }
        }
        const float osc = (mode == 0) ? QSCALE : 1.0f;
        bf16_t* dst = (mode == 0) ? Qb : Kb;
        const int ld = (mode == 0) ? NH * HD : KVDIM;
#pragma unroll
        for (int i = 0; i < 2; ++i)
#pragma unroll
            for (int j = 0; j < 4; ++j) {
                int row = m0 + w * 32 + i * 16 + q4 * 4;
                int col = nc + j * 16 + n16;
#pragma unroll
                for (int r = 0; r < 4; ++r)
                    dst[(size_t)(row + r) * ld + col] = (bf16_t)(acc[i][j][r] * osc);
            }
    } else {
        // ---- V: store transposed, 4 consecutive rows per lane contiguous ----
#pragma unroll
        for (int i = 0; i < 2; ++i)
#pragma unroll
            for (int j = 0; j < 4; ++j) {
                int row = m0 + w * 32 + i * 16 + q4 * 4;
                int col = nc + j * 16 + n16;
#pragma unroll
                for (int r = 0; r < 4; ++r)
                    Vt[(size_t)col * SEQ + row + r] = (bf16_t)acc[i][j][r];
            }
    }
}

// ---------------------------------------------------------------------------
// O projection, 128x64 tiles (512 blocks = 2/CU), direct stores (R11 best).
// ---------------------------------------------------------------------------
__global__ __launch_bounds__(256) void o_gemm(const bf16_t* __restrict__ A,
                                              const bf16_t* __restrict__ Bw,
                                              float* __restrict__ C)
{
    __shared__ alignas(16) bf16_t sa[128 * 32];
    __shared__ alignas(16) bf16_t sb[64 * 32];
    const int t = threadIdx.x;
    const int lane = t & 63;
    const int w  = t >> 6;
    const int n16 = lane & 15;
    const int q4  = lane >> 4;
    f32x4 acc[2][4] = {};

    const int m0 = blockIdx.x * 128;
    const int n0 = blockIdx.y * 64;

    const int lrow = lane >> 2;          // 0..15
    const int lcol = (lane & 3) * 8;
    const bf16_t* ag = A  + (size_t)(m0 + w * 32 + lrow) * HID + lcol;
    const bf16_t* bg = Bw + (size_t)(n0 + w * 16 + lrow) * HID + lcol;
    bf16_t* la0 = &sa[(w * 32) * 32];
    bf16_t* la1 = &sa[(w * 32 + 16) * 32];
    bf16_t* lb0 = &sb[(w * 16) * 32];

    for (int k0 = 0; k0 < HID; k0 += 32) {
        load_lds16(ag + k0, la0);
        load_lds16(ag + k0 + (size_t)16 * HID, la1);
        load_lds16(bg + k0, lb0);
        __syncthreads();
        bf16x8 bfrag[4];
#pragma unroll
        for (int j = 0; j < 4; ++j)
            bfrag[j] = *(const bf16x8*)&sb[(j * 16 + n16) * 32 + q4 * 8];
#pragma unroll
        for (int i = 0; i < 2; ++i) {
            bf16x8 af = *(const bf16x8*)&sa[(w * 32 + i * 16 + n16) * 32 + q4 * 8];
#pragma unroll
            for (int j = 0; j < 4; ++j)
                acc[i][j] = __builtin_amdgcn_mfma_f32_16x16x32_bf16(af, bfrag[j], acc[i][j], 0, 0, 0);
        }
        __syncthreads();
    }

#pragma unroll
    for (int i = 0; i < 2; ++i)
#pragma unroll
        for (int j = 0; j < 4; ++j) {
            int row = m0 + w * 32 + i * 16 + q4 * 4;
            int col = n0 + j * 16 + n16;
#pragma unroll
            for (int r = 0; r < 4; ++r)
                C[(size_t)(row + r) * HID + col] = acc[i][j][r];
        }
}

// ---------------------------------------------------------------------------
// MFMA causal flash attention — R11 structure (Bq=64, 128-kv staging per
// barrier pair, 40 KB LDS, no online softmax, deferred normalize) with:
//  (a) raw v_exp_f32 via EXPFN (log2e folded into Q pre-scale),
//  (b) l accumulated by ones-MFMA: acc_l = mfma(pf, ones8, acc_l) — D[q][*]
//      = row-sum of P, landing in the SAME C-layout rows as acc, so the
//      epilogue is linv[r]=1/acc_l[r] with no adds and no shuffle reduce.
// ---------------------------------------------------------------------------
__global__ __launch_bounds__(256) void attn_mfma(const bf16_t* __restrict__ Qm,
                                                 const bf16_t* __restrict__ Km,
                                                 const bf16_t* __restrict__ Vt,
                                                 bf16_t* __restrict__ Om)
{
    const int h   = blockIdx.x & (NH - 1);
    const int qt  = (SEQ / 64 - 1) - (blockIdx.x >> 5);   // heavy first
    const int q0  = qt * 64;
    const int kvh = h >> 2;            // H/KVH = 4
    const int t   = threadIdx.x;
    const int w   = t >> 6;
    const int lane = t & 63;
    const int n16 = lane & 15;
    const int q4  = lane >> 4;

    __shared__ alignas(16) bf16_t kA[128 * 32];
    __shared__ alignas(16) bf16_t kB[128 * 32];
    __shared__ alignas(16) bf16_t vc0[64 * 32], vc1[64 * 32];
    __shared__ alignas(16) bf16_t vc2[64 * 32], vc3[64 * 32];
    __shared__ alignas(16) bf16_t psA[4][16 * 32];
    __shared__ alignas(16) bf16_t psB[4][16 * 32];

    const int qrow = q0 + w * 16 + n16;
    const bf16_t* qbase = Qm + (size_t)qrow * HID + h * HD;
    const bf16x8 qf0 = *(const bf16x8*)(qbase + q4 * 8);
    const bf16x8 qf1 = *(const bf16x8*)(qbase + 32 + q4 * 8);

    f32x4 acc[4] = {};
    f32x4 acc_l = {};                    // row-sums of P via ones-MFMA
    const bf16_t one = (bf16_t)1.0f;
    const bf16x8 ones8 = {one, one, one, one, one, one, one, one};

    const int srow = lane >> 2;
    const int scol = (lane & 3) * 8;
    const bf16_t* kg = Km + (size_t)kvh * HD + scol;
    const bf16_t* vg = Vt + (size_t)(kvh * HD) * SEQ;

    const int rowg0 = q0 + w * 16 + q4 * 4;
    const int nhalf = qt + 1;

    for (int kb = 0; kb * 2 < nhalf; ++kb) {
        const int k0 = kb * 128;
        {
            const int r0 = w * 16 + srow;
            const bf16_t* kp0 = kg + (size_t)(k0 + r0) * KVDIM;
            const bf16_t* kp1 = kg + (size_t)(k0 + 64 + r0) * KVDIM;
            load_lds16(kp0,      &kA[(w * 16) * 32]);
            load_lds16(kp0 + 32, &kB[(w * 16) * 32]);
            load_lds16(kp1,      &kA[(64 + w * 16) * 32]);
            load_lds16(kp1 + 32, &kB[(64 + w * 16) * 32]);
            const bf16_t* vp = vg + (size_t)r0 * SEQ + k0 + scol;
            load_lds16(vp,      &vc0[(w * 16) * 32]);
            load_lds16(vp + 32, &vc1[(w * 16) * 32]);
            load_lds16(vp + 64, &vc2[(w * 16) * 32]);
            load_lds16(vp + 96, &vc3[(w * 16) * 32]);
        }
        __syncthreads();

#pragma unroll
        for (int hh = 0; hh < 2; ++hh) {
            const int gh = 2 * kb + hh;
            if (gh >= nhalf) break;                        // wave-uniform
            const bf16_t* kAh = &kA[hh * 64 * 32];
            const bf16_t* kBh = &kB[hh * 64 * 32];
            const bf16_t* vAh = hh ? vc2 : vc0;
            const bf16_t* vBh = hh ? vc3 : vc1;

            // ---- S' = Q' K^T (log2-domain scores) ----
            f32x4 st[4];
#pragma unroll
            for (int jt = 0; jt < 4; ++jt) {
                bf16x8 kf0 = *(const bf16x8*)&kAh[(jt * 16 + n16) * 32 + q4 * 8];
                bf16x8 kf1 = *(const bf16x8*)&kBh[(jt * 16 + n16) * 32 + q4 * 8];
                f32x4 s = {};
                s = __builtin_amdgcn_mfma_f32_16x16x32_bf16(qf0, kf0, s, 0, 0, 0);
                s = __builtin_amdgcn_mfma_f32_16x16x32_bf16(qf1, kf1, s, 0, 0, 0);
                st[jt] = s;
            }

            // ---- causal mask: diagonal half only ----
            if (gh == qt) {
#pragma unroll
                for (int jt = 0; jt < 4; ++jt) {
                    int colg = gh * 64 + jt * 16 + n16;
#pragma unroll
                    for (int r = 0; r < 4; ++r)
                        if (colg > rowg0 + r) st[jt][r] = -1e30f;
                }
            }

            // ---- exp (raw v_exp_f32 path) ----
#pragma unroll
            for (int jt = 0; jt < 4; ++jt)
#pragma unroll
                for (int r = 0; r < 4; ++r)
                    st[jt][r] = EXPFN(st[jt][r]);

            // ---- P: C-layout regs -> per-wave LDS (A-layout source) ----
#pragma unroll
            for (int jt = 0; jt < 4; ++jt) {
                bf16_t* ph = (jt < 2) ? psA[w] : psB[w];
                int c16 = (jt & 1) * 16;
#pragma unroll
                for (int r = 0; r < 4; ++r)
                    ph[(q4 * 4 + r) * 32 + c16 + n16] = (bf16_t)st[jt][r];
            }
            bf16x8 pf0 = *(const bf16x8*)&psA[w][n16 * 32 + q4 * 8];
            bf16x8 pf1 = *(const bf16x8*)&psB[w][n16 * 32 + q4 * 8];

            // ---- l += row-sum(P) via ones-MFMA (lands in acc C-layout) ----
            acc_l = __builtin_amdgcn_mfma_f32_16x16x32_bf16(pf0, ones8, acc_l, 0, 0, 0);
            acc_l = __builtin_amdgcn_mfma_f32_16x16x32_bf16(pf1, ones8, acc_l, 0, 0, 0);

            // ---- O += P V (unnormalized) ----
#pragma unroll
            for (int jd = 0; jd < 4; ++jd) {
                bf16x8 vf0 = *(const bf16x8*)&vAh[(jd * 16 + n16) * 32 + q4 * 8];
                bf16x8 vf1 = *(const bf16x8*)&vBh[(jd * 16 + n16) * 32 + q4 * 8];
                acc[jd] = __builtin_amdgcn_mfma_f32_16x16x32_bf16(pf0, vf0, acc[jd], 0, 0, 0);
                acc[jd] = __builtin_amdgcn_mfma_f32_16x16x32_bf16(pf1, vf1, acc[jd], 0, 0, 0);
            }
        }
        __syncthreads();
    }

    // ---- normalize + store (l already per-row in acc_l; no reduction) ----
    float linv[4];
#pragma unroll
    for (int r = 0; r < 4; ++r) linv[r] = 1.0f / acc_l[r];
#pragma unroll
    for (int jd = 0; jd < 4; ++jd)
#pragma unroll
        for (int r = 0; r < 4; ++r) {
            int rowg = rowg0 + r;
            Om[(size_t)rowg * HID + h * HD + jd * 16 + n16] = (bf16_t)(acc[jd][r] * linv[r]);
        }
}

// ---------------------------------------------------------------------------
extern "C" void kernel_launch(void* const* d_in, const int* in_sizes, int n_in,
                              void* d_out, int out_size, void* d_ws, size_t ws_size,
                              hipStream_t stream)
{
    const float* X  = (const float*)d_in[0];
    const float* Wq = (const float*)d_in[1];
    const float* Wk = (const float*)d_in[2];
    const float* Wv = (const float*)d_in[3];
    const float* Wo = (const float*)d_in[4];
    float* out = (float*)d_out;

    bf16_t* Xb  = (bf16_t*)d_ws;                      // [SEQ][HID]     8 MB
    bf16_t* Wqb = Xb  + (size_t)NX;                   // [2048][2048]   8 MB
    bf16_t* Wkb = Wqb + (size_t)NWQ;                  // [512][2048]    2 MB
    bf16_t* Wvb = Wkb + (size_t)NWK;                  // [512][2048]    2 MB
    bf16_t* Wob = Wvb + (size_t)NWV;                  // [2048][2048]   8 MB
    bf16_t* Qb  = Wob + (size_t)NWO;                  // [SEQ][NH*HD]   8 MB (pre-scaled QSCALE)
    bf16_t* Kb  = Qb  + (size_t)SEQ * (NH * HD);      // [SEQ][KVDIM]   2 MB
    bf16_t* Vt  = Kb  + (size_t)SEQ * KVDIM;          // [KVDIM][SEQ]   2 MB
    bf16_t* Ob  = Vt  + (size_t)SEQ * KVDIM;          // [SEQ][NH*HD]   8 MB

    dim3 blk(256);

    // one-shot fp32 -> bf16 conversion of all operands
    cvt_all<<<dim3((NTOT / 8 + 255) / 256), blk, 0, stream>>>(X, Wq, Wk, Wv, Wo, Xb, Wqb, Wkb, Wvb, Wob);

    // fused QKV projection + RoPE (128x64 tiles, 768 blocks = 3/CU)
    qkv_gemm<<<dim3(SEQ / 128, (NH * HD + 2 * KVDIM) / 64), blk, 0, stream>>>(Xb, Wqb, Wkb, Wvb, Qb, Kb, Vt);

    // causal GQA attention (R11 staging + raw-exp2 + ones-MFMA l)
    attn_mfma<<<dim3((SEQ / 64) * NH), blk, 0, stream>>>(Qb, Kb, Vt, Ob);

    // output projection -> d_out (128x64 tiles, direct stores)
    o_gemm<<<dim3(SEQ / 128, HID / 64), blk, 0, stream>>>(Ob, Wob, out);
}